// Round 4
// baseline (679.877 us; speedup 1.0000x reference)
//
#include <hip/hip_runtime.h>

typedef __bf16 bf16;
typedef __bf16 bf16x8 __attribute__((ext_vector_type(8)));
typedef float f32x4 __attribute__((ext_vector_type(4)));

#define CCH 128  // channels (all layers 128 -> 128)

// ---------------- prep: all 4 weight tensors (O,I,K) fp32 -> wT[k][o][i] bf16 ----------------
__global__ void k_prep_wall(const float* __restrict__ w1, const float* __restrict__ w2,
                            const float* __restrict__ w3, const float* __restrict__ w4,
                            bf16* __restrict__ o1, bf16* __restrict__ o2,
                            bf16* __restrict__ o3, bf16* __restrict__ o4) {
    int idx = blockIdx.x * 256 + threadIdx.x;
    const float* src; bf16* dst; int Kw; int r = idx;
    if (r < 15 * 16384) { src = w1; dst = o1; Kw = 15; }
    else if ((r -= 15 * 16384) < 12 * 16384) { src = w2; dst = o2; Kw = 12; }
    else if ((r -= 12 * 16384) < 7 * 16384) { src = w3; dst = o3; Kw = 7; }
    else if ((r -= 7 * 16384) < 4 * 16384) { src = w4; dst = o4; Kw = 4; }
    else return;
    int i = r & 127;
    int o = (r >> 7) & 127;
    int k = r >> 14;
    dst[r] = (bf16)src[(o * 128 + i) * Kw + k];
}

// ---------------- prep: centers fp32 -> padded bf16 [k][o][64] (zeros l>=59), plus ||c||^2 ----
__global__ void k_prep_c(const float* __restrict__ c, bf16* __restrict__ cbp,
                         float* __restrict__ cc) {
    int k = blockIdx.x;
    int tid = threadIdx.x;
    float s = 0.f;
    for (int idx = tid; idx < 128 * 64; idx += 256) {
        int o = idx >> 6;
        int l = idx & 63;
        float v = (l < 59) ? c[k * 7552 + o * 59 + l] : 0.f;
        bf16 b = (bf16)v;
        cbp[(size_t)(k * 128 + o) * 64 + l] = b;
        float fv = (float)b;
        s += fv * fv;
    }
    __shared__ float red[256];
    red[tid] = s;
    __syncthreads();
    for (int st = 128; st > 0; st >>= 1) {
        if (tid < st) red[tid] += red[tid + st];
        __syncthreads();
    }
    if (tid == 0) cc[k] = red[0];
}

// ---------------- conv layer: implicit GEMM, bf16 MFMA ----------------
// Staging: lane = 16 rows x 4 consecutive 16B chunks -> full-line coalesced
// global loads (16 lines/instr); LDS writes ~2-way bank aliased (free).
// K-loop: A register double-buffered global loads; B from swizzled LDS.
template <int KW, int LIN_S, int LIN_V, int LOUT_S, int LT, bool ACT, bool IN_F32, int MINB>
__global__ __launch_bounds__(256, MINB) void k_conv(
    const void* __restrict__ in_, const bf16* __restrict__ wT,
    const float* __restrict__ bias, bf16* __restrict__ out) {
    constexpr int P = (LT - 1) * 2 + KW;   // input positions needed by this tile
    constexpr int PP = (P + 7) & ~7;       // padded to vec width
    constexpr int VW = IN_F32 ? 4 : 8;     // elems per 16B staging load
    constexpr int NV = PP / VW;            // 16B chunks per channel row
    constexpr int NVB = (NV + 3) / 4;      // chunk groups (4 lanes each)
    constexpr bool VG = (NV & 3) != 0;
    constexpr int WLS = LT / 2;            // l-span per wave
    constexpr int NLT = WLS / 16;          // 16-wide l-tiles per wave
    constexpr int SE = LT + 8;             // epilogue LDS row stride
    constexpr int SM = (PP * 64 > 128 * SE) ? PP * 64 : 128 * SE;
    __shared__ __align__(16) bf16 smem[SM];

    const int n = blockIdx.y;
    const int l0 = blockIdx.x * LT;
    const int p0 = l0 * 2;
    const int tid = threadIdx.x;
    const int wid = tid >> 6;
    const int lane = tid & 63;
    const int quad = lane >> 4;
    const int l15 = lane & 15;
    const int wave_o = (wid >> 1) * 64;   // 2x2 wave grid: 64o x WLS l per wave
    const int wave_l = (wid & 1) * WLS;

    const float* __restrict__ inF = (const float*)in_;
    const bf16* __restrict__ inB = (const bf16*)in_;

    f32x4 acc[4][NLT];
#pragma unroll
    for (int a = 0; a < 4; ++a)
#pragma unroll
        for (int b = 0; b < NLT; ++b) acc[a][b] = (f32x4){0.f, 0.f, 0.f, 0.f};

    bf16x8 afr[2][4];
    const int aoff = (wave_o + l15) * CCH + quad * 8;  // lane part of A address

    const int si = wid * 16 + (lane >> 2);  // staging: local channel 0..63
    const int c4 = lane & 3;                // staging: chunk-within-group

#pragma unroll 1
    for (int phase = 0; phase < 2; ++phase) {
        const int cbase = phase * 64;
        __syncthreads();  // protect smem against overwrite (phase 1)

        // prefetch A for j=0 of this phase (global; overlaps staging)
        {
            const bf16* wp = wT + aoff + cbase;
#pragma unroll
            for (int ot = 0; ot < 4; ++ot) afr[0][ot] = *(const bf16x8*)(wp + ot * 16 * CCH);
        }

        // stage: rows [cbase+si], chunks v = vb*4 + c4 (consecutive lanes -> 64B lines)
        {
            const char* rowb = IN_F32
                ? (const char*)(inF + (size_t)(n * CCH + cbase + si) * LIN_S)
                : (const char*)(inB + (size_t)(n * CCH + cbase + si) * LIN_S);
#pragma unroll
            for (int vb = 0; vb < NVB; ++vb) {
                int v = vb * 4 + c4;
                if (!VG || v < NV) {
                    int gp0 = p0 + v * VW;
                    float vals[VW];
                    if (gp0 + VW <= LIN_V) {
                        if (IN_F32) {
                            f32x4 t = *(const f32x4*)((const float*)rowb + gp0);
#pragma unroll
                            for (int e = 0; e < VW; ++e) vals[e] = t[e & 3];
                        } else {
                            bf16x8 t = *(const bf16x8*)((const bf16*)rowb + gp0);
#pragma unroll
                            for (int e = 0; e < VW; ++e) vals[e] = (float)t[e & 7];
                        }
                    } else {
#pragma unroll
                        for (int e = 0; e < VW; ++e) {
                            int gp = gp0 + e;
                            vals[e] = 0.f;
                            if (gp < LIN_V)
                                vals[e] = IN_F32 ? ((const float*)rowb)[gp]
                                                 : (float)((const bf16*)rowb)[gp];
                        }
                    }
#pragma unroll
                    for (int e = 0; e < VW; ++e) {
                        int p = v * VW + e;
                        int slot = (si >> 3) ^ ((p >> 1) & 7);
                        smem[p * 64 + slot * 8 + (si & 7)] = (bf16)vals[e];
                    }
                }
            }
        }
        __syncthreads();

        // K-loop: j = (k, ic) flattened; A double-buffered one iter ahead
#pragma unroll 2
        for (int j = 0; j < 2 * KW; ++j) {
            if (j + 1 < 2 * KW) {
                int k1 = (j + 1) >> 1;
                const bf16* wp = wT + (size_t)k1 * CCH * CCH + aoff + cbase + ((j + 1) & 1) * 32;
#pragma unroll
                for (int ot = 0; ot < 4; ++ot)
                    afr[(j + 1) & 1][ot] = *(const bf16x8*)(wp + ot * 16 * CCH);
            }
            const int k = j >> 1;
            const int icq = (j & 1) * 4 + quad;  // (ic*32 + quad*8) >> 3
#pragma unroll
            for (int lt = 0; lt < NLT; ++lt) {
                int p = (wave_l + lt * 16 + l15) * 2 + k;
                int slot = icq ^ ((p >> 1) & 7);
                bf16x8 bfr = *(const bf16x8*)(smem + p * 64 + slot * 8);
#pragma unroll
                for (int ot = 0; ot < 4; ++ot)
                    acc[ot][lt] = __builtin_amdgcn_mfma_f32_16x16x32_bf16(
                        afr[j & 1][ot], bfr, acc[ot][lt], 0, 0, 0);
            }
        }
    }

    // ---- epilogue: bias+act, LDS transpose, wide contiguous stores ----
    __syncthreads();  // all B-reads of smem done
#pragma unroll
    for (int ot = 0; ot < 4; ++ot) {
        const int o0 = wave_o + ot * 16 + quad * 4;
#pragma unroll
        for (int lt = 0; lt < NLT; ++lt) {
            const int l = wave_l + lt * 16 + l15;
#pragma unroll
            for (int r = 0; r < 4; ++r) {
                float v = acc[ot][lt][r] + bias[o0 + r];
                if (ACT) v = (v > 0.f) ? v : 0.1f * v;
                smem[(o0 + r) * SE + l] = (bf16)v;
            }
        }
    }
    __syncthreads();
    constexpr int GPR = LT / 8;  // 16B groups per o-row (pow2)
#pragma unroll
    for (int it = 0; it < 128 * GPR / 256; ++it) {
        int unit = tid + it * 256;
        int o = unit / GPR;
        int g = unit & (GPR - 1);
        bf16x8 vv = *(const bf16x8*)(smem + o * SE + g * 8);
        *(bf16x8*)(out + (size_t)(n * CCH + o) * LOUT_S + l0 + g * 8) = vv;
    }
}

// ---------------- fused conv4 + distances + Student-t assignment ----------------
// One block per batch row n. conv4 (K=4, 121->59, LT=64 covers all l), z kept in
// LDS fp32 (zeros l>=59), then per-thread t = sum(z^2) - 2*sum(z*c) folds ||z||^2
// into the part reduction: d2 = sum_parts(t) + ||c||^2.
__global__ __launch_bounds__(256, 2) void k_conv4_dist(
    const bf16* __restrict__ in_, const bf16* __restrict__ wT,
    const float* __restrict__ bias, const bf16* __restrict__ cbp,
    const float* __restrict__ cc, float* __restrict__ out) {
    constexpr int KW = 4, LIN_S = 128, LIN_V = 121, LT = 64;
    constexpr int PP = 136, NV = 17, NVB = 5;  // P=130
    constexpr int SE = 72;
    __shared__ __align__(16) bf16 smem[PP * 64];     // staging
    __shared__ __align__(16) float zmem[128 * SE];   // z fp32
    __shared__ float red[256];
    __shared__ float qsh[64];

    const int n = blockIdx.x;
    const int tid = threadIdx.x;
    const int wid = tid >> 6;
    const int lane = tid & 63;
    const int quad = lane >> 4;
    const int l15 = lane & 15;
    const int wave_o = (wid >> 1) * 64;
    const int wave_l = (wid & 1) * 32;

    const bf16* __restrict__ inB = (const bf16*)in_;

    f32x4 acc[4][2];
#pragma unroll
    for (int a = 0; a < 4; ++a)
#pragma unroll
        for (int b = 0; b < 2; ++b) acc[a][b] = (f32x4){0.f, 0.f, 0.f, 0.f};

    bf16x8 afr[2][4];
    const int aoff = (wave_o + l15) * CCH + quad * 8;
    const int si = wid * 16 + (lane >> 2);
    const int c4 = lane & 3;

#pragma unroll 1
    for (int phase = 0; phase < 2; ++phase) {
        const int cbase = phase * 64;
        __syncthreads();
        {
            const bf16* wp = wT + aoff + cbase;
#pragma unroll
            for (int ot = 0; ot < 4; ++ot) afr[0][ot] = *(const bf16x8*)(wp + ot * 16 * CCH);
        }
        {
            const bf16* rowb = inB + (size_t)(n * CCH + cbase + si) * LIN_S;
#pragma unroll
            for (int vb = 0; vb < NVB; ++vb) {
                int v = vb * 4 + c4;
                if (v < NV) {
                    int gp0 = v * 8;
                    float vals[8];
                    if (gp0 + 8 <= LIN_V) {
                        bf16x8 t = *(const bf16x8*)(rowb + gp0);
#pragma unroll
                        for (int e = 0; e < 8; ++e) vals[e] = (float)t[e];
                    } else {
#pragma unroll
                        for (int e = 0; e < 8; ++e) {
                            int gp = gp0 + e;
                            vals[e] = (gp < LIN_V) ? (float)rowb[gp] : 0.f;
                        }
                    }
#pragma unroll
                    for (int e = 0; e < 8; ++e) {
                        int p = v * 8 + e;
                        int slot = (si >> 3) ^ ((p >> 1) & 7);
                        smem[p * 64 + slot * 8 + (si & 7)] = (bf16)vals[e];
                    }
                }
            }
        }
        __syncthreads();
#pragma unroll 2
        for (int j = 0; j < 2 * KW; ++j) {
            if (j + 1 < 2 * KW) {
                int k1 = (j + 1) >> 1;
                const bf16* wp = wT + (size_t)k1 * CCH * CCH + aoff + cbase + ((j + 1) & 1) * 32;
#pragma unroll
                for (int ot = 0; ot < 4; ++ot)
                    afr[(j + 1) & 1][ot] = *(const bf16x8*)(wp + ot * 16 * CCH);
            }
            const int k = j >> 1;
            const int icq = (j & 1) * 4 + quad;
#pragma unroll
            for (int lt = 0; lt < 2; ++lt) {
                int p = (wave_l + lt * 16 + l15) * 2 + k;
                int slot = icq ^ ((p >> 1) & 7);
                bf16x8 bfr = *(const bf16x8*)(smem + p * 64 + slot * 8);
#pragma unroll
                for (int ot = 0; ot < 4; ++ot)
                    acc[ot][lt] = __builtin_amdgcn_mfma_f32_16x16x32_bf16(
                        afr[j & 1][ot], bfr, acc[ot][lt], 0, 0, 0);
            }
        }
    }

    // epilogue -> z in LDS fp32, zeros for l>=59 (pads match zero-padded centers)
#pragma unroll
    for (int ot = 0; ot < 4; ++ot) {
        const int o0 = wave_o + ot * 16 + quad * 4;
#pragma unroll
        for (int lt = 0; lt < 2; ++lt) {
            const int l = wave_l + lt * 16 + l15;
#pragma unroll
            for (int r = 0; r < 4; ++r) {
                float v = acc[ot][lt][r] + bias[o0 + r];
                zmem[(o0 + r) * SE + l] = (l < 59) ? v : 0.f;
            }
        }
    }
    __syncthreads();

    // dist: thread = (center k = tid>>2, part = tid&3 covering 32 o-rows)
    const int kc = tid >> 2;
    const int part = tid & 3;
    const bf16* cr = cbp + (size_t)(kc * 128 + part * 32) * 64;
    const float* zr = zmem + part * 32 * SE;
    float t = 0.f;
#pragma unroll 2
    for (int o = 0; o < 32; ++o) {
#pragma unroll
        for (int g = 0; g < 8; ++g) {
            bf16x8 cv = *(const bf16x8*)(cr + o * 64 + g * 8);
            f32x4 z0 = *(const f32x4*)(zr + o * SE + g * 8);
            f32x4 z1 = *(const f32x4*)(zr + o * SE + g * 8 + 4);
#pragma unroll
            for (int e = 0; e < 4; ++e) t += z0[e] * (z0[e] - 2.f * (float)cv[e]);
#pragma unroll
            for (int e = 0; e < 4; ++e) t += z1[e] * (z1[e] - 2.f * (float)cv[4 + e]);
        }
    }
    red[tid] = t;
    __syncthreads();
    if (tid < 64) {
        float d2 = red[tid * 4] + red[tid * 4 + 1] + red[tid * 4 + 2] + red[tid * 4 + 3]
                   + cc[tid];
        qsh[tid] = 1.f / (1.f + d2);  // ALPHA=1, exponent (ALPHA+1)/2 == 1
    }
    __syncthreads();
    if (tid < 64) {
        float q = qsh[tid];
        float tot = q;
        for (int o = 32; o > 0; o >>= 1) tot += __shfl_down(tot, o);
        tot = __shfl(tot, 0);
        out[n * 64 + tid] = q / tot;
    }
}

// ---------------- launcher ----------------
extern "C" void kernel_launch(void* const* d_in, const int* in_sizes, int n_in,
                              void* d_out, int out_size, void* d_ws, size_t ws_size,
                              hipStream_t stream) {
    (void)in_sizes; (void)n_in; (void)out_size; (void)ws_size;
    const float* x   = (const float*)d_in[0];
    const float* w1  = (const float*)d_in[1];
    const float* b1  = (const float*)d_in[2];
    const float* w2  = (const float*)d_in[3];
    const float* b2  = (const float*)d_in[4];
    const float* w3  = (const float*)d_in[5];
    const float* b3  = (const float*)d_in[6];
    const float* w4  = (const float*)d_in[7];
    const float* b4  = (const float*)d_in[8];
    const float* cen = (const float*)d_in[9];
    float* out = (float*)d_out;

    char* ws = (char*)d_ws;
    size_t off = 0;
    auto alloc = [&](size_t bytes) -> void* {
        void* p = ws + off;
        off += (bytes + 255) & ~(size_t)255;
        return p;
    };
    bf16* wT1 = (bf16*)alloc((size_t)15 * 16384 * sizeof(bf16));
    bf16* wT2 = (bf16*)alloc((size_t)12 * 16384 * sizeof(bf16));
    bf16* wT3 = (bf16*)alloc((size_t)7 * 16384 * sizeof(bf16));
    bf16* wT4 = (bf16*)alloc((size_t)4 * 16384 * sizeof(bf16));
    bf16* cbp = (bf16*)alloc((size_t)64 * 128 * 64 * sizeof(bf16));
    float* cc = (float*)alloc(64 * sizeof(float));
    // padded intermediates: strides 512/256/128 (16B-aligned rows)
    bf16* h1  = (bf16*)alloc((size_t)256 * 128 * 512 * sizeof(bf16));
    bf16* h2  = (bf16*)alloc((size_t)256 * 128 * 256 * sizeof(bf16));
    bf16* h3  = h1;  // reuse: h1 dead after conv2 (needs 128-stride)

    k_prep_wall<<<(38 * 16384 + 255) / 256, 256, 0, stream>>>(w1, w2, w3, w4, wT1, wT2, wT3, wT4);
    k_prep_c<<<64, 256, 0, stream>>>(cen, cbp, cc);

    // conv1: 1024 -> 505(512) K=15, LeakyReLU, fp32 input; LT=64 -> 2048 blocks
    k_conv<15, 1024, 1024, 512, 64, true, true, 5>
        <<<dim3(8, 256), 256, 0, stream>>>(x, wT1, b1, h1);
    // conv2: 505(512) -> 247(256) K=12, LeakyReLU; LT=64 -> 1024 blocks
    k_conv<12, 512, 505, 256, 64, true, false, 5>
        <<<dim3(4, 256), 256, 0, stream>>>(h1, wT2, b2, h2);
    // conv3: 247(256) -> 121(128) K=7, LeakyReLU; LT=32 -> 1024 blocks
    k_conv<7, 256, 247, 128, 32, true, false, 5>
        <<<dim3(4, 256), 256, 0, stream>>>(h2, wT3, b3, h3);
    // conv4 (121(128) -> 59, K=4) fused with distances + softmax-normalize
    k_conv4_dist<<<256, 256, 0, stream>>>(h3, wT4, b4, cbp, cc, out);
}

// Round 5
// 625.226 us; speedup vs baseline: 1.0874x; 1.0874x over previous
//
#include <hip/hip_runtime.h>

typedef __bf16 bf16;
typedef __bf16 bf16x4 __attribute__((ext_vector_type(4)));
typedef __bf16 bf16x8 __attribute__((ext_vector_type(8)));
typedef float f32x4 __attribute__((ext_vector_type(4)));

#define CCH 128  // channels (all layers 128 -> 128)

// ---------------- prep: all 4 weight tensors (O,I,K) fp32 -> wT[k][o][i] bf16 ----------------
__global__ void k_prep_wall(const float* __restrict__ w1, const float* __restrict__ w2,
                            const float* __restrict__ w3, const float* __restrict__ w4,
                            bf16* __restrict__ o1, bf16* __restrict__ o2,
                            bf16* __restrict__ o3, bf16* __restrict__ o4) {
    int idx = blockIdx.x * 256 + threadIdx.x;
    const float* src; bf16* dst; int Kw; int r = idx;
    if (r < 15 * 16384) { src = w1; dst = o1; Kw = 15; }
    else if ((r -= 15 * 16384) < 12 * 16384) { src = w2; dst = o2; Kw = 12; }
    else if ((r -= 12 * 16384) < 7 * 16384) { src = w3; dst = o3; Kw = 7; }
    else if ((r -= 7 * 16384) < 4 * 16384) { src = w4; dst = o4; Kw = 4; }
    else return;
    int i = r & 127;
    int o = (r >> 7) & 127;
    int k = r >> 14;
    dst[r] = (bf16)src[(o * 128 + i) * Kw + k];
}

// ---------------- prep: centers fp32 -> bf16 [k][l(64, zero-pad l>=59)][o], plus ||c||^2 ----
__global__ void k_prep_c(const float* __restrict__ c, bf16* __restrict__ cbp,
                         float* __restrict__ cc) {
    int k = blockIdx.x;
    int tid = threadIdx.x;
    float s = 0.f;
    for (int idx = tid; idx < 64 * 128; idx += 256) {
        int l = idx >> 7;
        int o = idx & 127;
        float v = (l < 59) ? c[k * 7552 + o * 59 + l] : 0.f;
        bf16 b = (bf16)v;
        cbp[(size_t)k * 64 * 128 + idx] = b;
        float fv = (float)b;
        s += fv * fv;
    }
    __shared__ float red[256];
    red[tid] = s;
    __syncthreads();
    for (int st = 128; st > 0; st >>= 1) {
        if (tid < st) red[tid] += red[tid + st];
        __syncthreads();
    }
    if (tid == 0) cc[k] = red[0];
}

// ---------------- conv layer: implicit GEMM, bf16 MFMA, position-major ----------------
// Input  (IN_CL_F32): x [n][128][1024] fp32 (conv1)  else h [n][row][128] bf16.
// Output: [n][l][o=128] bf16, row stride 256B.
// LDS: position rows of 256B, chunk c at slot sc=(c&8)|((c&7)^((p>>1)&7)):
//   staging writes and B-frag b128 reads both <=2-way bank aliased (free).
// K-loop j=(ktap, kchunk): A (weights) register double-buffered global 16B loads.
// minb=4: 128 regs/wave -- the no-spill boundary measured in R4.
template <int KW, int IN_CAP, int OUT_ROWS, int LT, bool ACT, bool IN_CL_F32>
__global__ __launch_bounds__(256, 4) void k_conv(
    const void* __restrict__ in_, const bf16* __restrict__ wT,
    const float* __restrict__ bias, bf16* __restrict__ out) {
    constexpr int P = (LT - 1) * 2 + KW;    // input positions needed by this tile
    constexpr int PP = IN_CL_F32 ? ((P + 3) & ~3) : P;  // conv1 staging writes p in 4-groups
    constexpr int WLS = LT / 2;             // l-span per wave
    constexpr int NLT = WLS / 16;           // 16-wide l-tiles per wave
    constexpr int ESE = 136;                // epilogue [l][o] stride (o=128 + 8 pad)
    constexpr int SMELE = (PP * 128 > LT * ESE) ? PP * 128 : LT * ESE;
    __shared__ __align__(16) bf16 smem[SMELE];

    const int n = blockIdx.y;
    const int l0 = blockIdx.x * LT;
    const int p0 = l0 * 2;
    const int tid = threadIdx.x;
    const int wid = tid >> 6;
    const int lane = tid & 63;
    const int quad = lane >> 4;
    const int l15 = lane & 15;
    const int wave_o = (wid >> 1) * 64;   // 2x2 wave grid: 64o x WLS l per wave
    const int wave_l = (wid & 1) * WLS;

    f32x4 acc[4][NLT];
#pragma unroll
    for (int a = 0; a < 4; ++a)
#pragma unroll
        for (int b = 0; b < NLT; ++b) acc[a][b] = (f32x4){0.f, 0.f, 0.f, 0.f};

    bf16x8 afr[2][4];
    const int aoff = (wave_o + l15) * CCH + quad * 8;  // lane part of A address

    // prefetch A for j=0 (global; overlaps staging)
    {
        const bf16* wp = wT + aoff;  // ktap=0, kchunk=0
#pragma unroll
        for (int ot = 0; ot < 4; ++ot) afr[0][ot] = *(const bf16x8*)(wp + ot * 16 * CCH);
    }

    // ---- staging ----
    if (IN_CL_F32) {
        // conv1: x fp32 [n][c][1024]; chunks of 4 positions along each channel row,
        // scalar-scattered (cvt bf16) into position-major swizzled LDS.
        constexpr int NCHK = (PP + 3) / 4;        // 16B chunks per channel row
        constexpr int UNITS = 128 * NCHK;
        constexpr int NIT = (UNITS + 255) / 256;
        const float* inF = (const float*)in_;
#pragma unroll
        for (int it = 0; it < NIT; ++it) {
            int u = tid + it * 256;
            if ((UNITS & 255) == 0 || u < UNITS) {
                int i = u / NCHK;                  // channel 0..127
                int v = u - i * NCHK;              // chunk (consecutive tid -> coalesced)
                int gp0 = p0 + v * 4;
                const float* row = inF + ((size_t)n * CCH + i) * 1024;
                float vals[4];
                if (gp0 + 4 <= 1024) {
                    f32x4 t = *(const f32x4*)(row + gp0);
#pragma unroll
                    for (int e = 0; e < 4; ++e) vals[e] = t[e];
                } else {
#pragma unroll
                    for (int e = 0; e < 4; ++e)
                        vals[e] = (gp0 + e < 1024) ? row[gp0 + e] : 0.f;
                }
                int ch = i >> 3;                   // chunk-of-8-channels 0..15
#pragma unroll
                for (int e = 0; e < 4; ++e) {
                    int p = v * 4 + e;
                    int sc = (ch & 8) | ((ch & 7) ^ ((p >> 1) & 7));
                    smem[p * 128 + sc * 8 + (i & 7)] = (bf16)vals[e];
                }
            }
        }
    } else {
        // conv2/3: position-major bf16 input; b128 load + b128 swizzled LDS write.
        // No validity guard: out-of-tile garbage only feeds invalid output columns.
        constexpr int UNITS = P * 16;
        constexpr int NIT = (UNITS + 255) / 256;
        const bf16* base = (const bf16*)in_ + ((size_t)n * IN_CAP + p0) * CCH;
#pragma unroll
        for (int it = 0; it < NIT; ++it) {
            int u = tid + it * 256;
            if ((UNITS & 255) == 0 || u < UNITS) {
                int p = u >> 4;
                int c = u & 15;
                bf16x8 t = *(const bf16x8*)(base + p * CCH + c * 8);
                int sc = (c & 8) | ((c & 7) ^ ((p >> 1) & 7));
                *(bf16x8*)(smem + p * 128 + sc * 8) = t;
            }
        }
    }
    __syncthreads();

    // ---- K-loop: j = (ktap, kchunk); A double-buffered one iter ahead ----
#pragma unroll 2
    for (int j = 0; j < 4 * KW; ++j) {
        if (j + 1 < 4 * KW) {
            int kt1 = (j + 1) >> 2;
            int i01 = ((j + 1) & 3) * 32;
            const bf16* wp = wT + (size_t)kt1 * CCH * CCH + aoff + i01;
#pragma unroll
            for (int ot = 0; ot < 4; ++ot)
                afr[(j + 1) & 1][ot] = *(const bf16x8*)(wp + ot * 16 * CCH);
        }
        const int ktap = j >> 2;
        const int c = (j & 3) * 4 + quad;   // chunk index 0..15
#pragma unroll
        for (int lt = 0; lt < NLT; ++lt) {
            int p = (wave_l + lt * 16 + l15) * 2 + ktap;
            int sc = (c & 8) | ((c & 7) ^ ((p >> 1) & 7));
            bf16x8 bfr = *(const bf16x8*)(smem + p * 128 + sc * 8);
#pragma unroll
            for (int ot = 0; ot < 4; ++ot)
                acc[ot][lt] = __builtin_amdgcn_mfma_f32_16x16x32_bf16(
                    afr[j & 1][ot], bfr, acc[ot][lt], 0, 0, 0);
        }
    }

    // ---- epilogue: bias+act -> LDS [l][o] -> contiguous 16B stores ----
    __syncthreads();  // staging reads done; smem reused
#pragma unroll
    for (int ot = 0; ot < 4; ++ot) {
        const int o0 = wave_o + ot * 16 + quad * 4;
        const f32x4 bv = *(const f32x4*)(bias + o0);
#pragma unroll
        for (int lt = 0; lt < NLT; ++lt) {
            const int l = wave_l + lt * 16 + l15;
            bf16x4 pk;
#pragma unroll
            for (int r = 0; r < 4; ++r) {
                float v = acc[ot][lt][r] + bv[r];
                if (ACT) v = (v > 0.f) ? v : 0.1f * v;
                pk[r] = (bf16)v;
            }
            *(bf16x4*)(smem + l * ESE + o0) = pk;
        }
    }
    __syncthreads();
    constexpr int SNIT = LT * 16 / 256;
    bf16* op = out + ((size_t)n * OUT_ROWS + l0) * CCH;
#pragma unroll
    for (int it = 0; it < SNIT; ++it) {
        int u = tid + it * 256;
        int l = u >> 4;
        int g = u & 15;
        *(bf16x8*)(op + l * CCH + g * 8) = *(const bf16x8*)(smem + l * ESE + g * 8);
    }
}

// ---------------- fused conv4 + distances + Student-t assignment ----------------
// One block per batch row n. conv4 (K=4, 121->59, LT=64), z kept in LDS bf16 [l][o]
// (zeros l>=59), then t = sum(z^2 - 2*z*c) folds ||z||^2 into the part reduction.
__global__ __launch_bounds__(256, 2) void k_conv4_dist(
    const bf16* __restrict__ in_, const bf16* __restrict__ wT,
    const float* __restrict__ bias, const bf16* __restrict__ cbp,
    const float* __restrict__ cc, float* __restrict__ out) {
    constexpr int KW = 4, LT = 64, P = 130, IN_CAP = 128;
    constexpr int ESE = 136;
    __shared__ __align__(16) bf16 smem[P * 128];
    __shared__ __align__(16) bf16 zmem[LT * ESE];
    __shared__ float red[256];
    __shared__ float qsh[64];

    const int n = blockIdx.x;
    const int tid = threadIdx.x;
    const int wid = tid >> 6;
    const int lane = tid & 63;
    const int quad = lane >> 4;
    const int l15 = lane & 15;
    const int wave_o = (wid >> 1) * 64;
    const int wave_l = (wid & 1) * 32;

    f32x4 acc[4][2];
#pragma unroll
    for (int a = 0; a < 4; ++a)
#pragma unroll
        for (int b = 0; b < 2; ++b) acc[a][b] = (f32x4){0.f, 0.f, 0.f, 0.f};

    bf16x8 afr[2][4];
    const int aoff = (wave_o + l15) * CCH + quad * 8;
    {
        const bf16* wp = wT + aoff;
#pragma unroll
        for (int ot = 0; ot < 4; ++ot) afr[0][ot] = *(const bf16x8*)(wp + ot * 16 * CCH);
    }
    {
        constexpr int UNITS = P * 16;  // 2080
        const bf16* base = in_ + (size_t)n * IN_CAP * CCH;
#pragma unroll
        for (int it = 0; it < (UNITS + 255) / 256; ++it) {
            int u = tid + it * 256;
            if (u < UNITS) {
                int p = u >> 4;
                int c = u & 15;
                bf16x8 t = *(const bf16x8*)(base + p * CCH + c * 8);
                int sc = (c & 8) | ((c & 7) ^ ((p >> 1) & 7));
                *(bf16x8*)(smem + p * 128 + sc * 8) = t;
            }
        }
    }
    __syncthreads();

#pragma unroll 2
    for (int j = 0; j < 4 * KW; ++j) {
        if (j + 1 < 4 * KW) {
            int kt1 = (j + 1) >> 2;
            const bf16* wp = wT + (size_t)kt1 * CCH * CCH + aoff + ((j + 1) & 3) * 32;
#pragma unroll
            for (int ot = 0; ot < 4; ++ot)
                afr[(j + 1) & 1][ot] = *(const bf16x8*)(wp + ot * 16 * CCH);
        }
        const int ktap = j >> 2;
        const int c = (j & 3) * 4 + quad;
#pragma unroll
        for (int lt = 0; lt < 2; ++lt) {
            int p = (wave_l + lt * 16 + l15) * 2 + ktap;
            int sc = (c & 8) | ((c & 7) ^ ((p >> 1) & 7));
            bf16x8 bfr = *(const bf16x8*)(smem + p * 128 + sc * 8);
#pragma unroll
            for (int ot = 0; ot < 4; ++ot)
                acc[ot][lt] = __builtin_amdgcn_mfma_f32_16x16x32_bf16(
                    afr[j & 1][ot], bfr, acc[ot][lt], 0, 0, 0);
        }
    }

    // epilogue -> z bf16 [l][o], zeros for l>=59 (pads match zero-padded centers)
#pragma unroll
    for (int ot = 0; ot < 4; ++ot) {
        const int o0 = wave_o + ot * 16 + quad * 4;
        const f32x4 bv = *(const f32x4*)(bias + o0);
#pragma unroll
        for (int lt = 0; lt < 2; ++lt) {
            const int l = wave_l + lt * 16 + l15;
            bf16x4 pk;
#pragma unroll
            for (int r = 0; r < 4; ++r) {
                float v = acc[ot][lt][r] + bv[r];
                pk[r] = (l < 59) ? (bf16)v : (bf16)0.f;
            }
            *(bf16x4*)(zmem + l * ESE + o0) = pk;
        }
    }
    __syncthreads();

    // dist: thread = (center kc = tid>>2, part = tid&3 covering 16 l-rows)
    const int kc = tid >> 2;
    const int part = tid & 3;
    const bf16* cr = cbp + ((size_t)kc * 64 + part * 16) * 128;
    const bf16* zr = zmem + part * 16 * ESE;
    float t = 0.f;
#pragma unroll 2
    for (int l = 0; l < 16; ++l) {
#pragma unroll
        for (int g = 0; g < 16; ++g) {
            bf16x8 cv = *(const bf16x8*)(cr + l * 128 + g * 8);
            bf16x8 zv = *(const bf16x8*)(zr + l * ESE + g * 8);
#pragma unroll
            for (int e = 0; e < 8; ++e) {
                float zf = (float)zv[e];
                t += zf * (zf - 2.f * (float)cv[e]);
            }
        }
    }
    red[tid] = t;
    __syncthreads();
    if (tid < 64) {
        float d2 = red[tid * 4] + red[tid * 4 + 1] + red[tid * 4 + 2] + red[tid * 4 + 3]
                   + cc[tid];
        qsh[tid] = 1.f / (1.f + d2);  // ALPHA=1, exponent (ALPHA+1)/2 == 1
    }
    __syncthreads();
    if (tid < 64) {
        float q = qsh[tid];
        float tot = q;
        for (int o = 32; o > 0; o >>= 1) tot += __shfl_down(tot, o);
        tot = __shfl(tot, 0);
        out[n * 64 + tid] = q / tot;
    }
}

// ---------------- launcher ----------------
extern "C" void kernel_launch(void* const* d_in, const int* in_sizes, int n_in,
                              void* d_out, int out_size, void* d_ws, size_t ws_size,
                              hipStream_t stream) {
    (void)in_sizes; (void)n_in; (void)out_size; (void)ws_size;
    const float* x   = (const float*)d_in[0];
    const float* w1  = (const float*)d_in[1];
    const float* b1  = (const float*)d_in[2];
    const float* w2  = (const float*)d_in[3];
    const float* b2  = (const float*)d_in[4];
    const float* w3  = (const float*)d_in[5];
    const float* b3  = (const float*)d_in[6];
    const float* w4  = (const float*)d_in[7];
    const float* b4  = (const float*)d_in[8];
    const float* cen = (const float*)d_in[9];
    float* out = (float*)d_out;

    char* ws = (char*)d_ws;
    size_t off = 0;
    auto alloc = [&](size_t bytes) -> void* {
        void* p = ws + off;
        off += (bytes + 255) & ~(size_t)255;
        return p;
    };
    bf16* wT1 = (bf16*)alloc((size_t)15 * 16384 * sizeof(bf16));
    bf16* wT2 = (bf16*)alloc((size_t)12 * 16384 * sizeof(bf16));
    bf16* wT3 = (bf16*)alloc((size_t)7 * 16384 * sizeof(bf16));
    bf16* wT4 = (bf16*)alloc((size_t)4 * 16384 * sizeof(bf16));
    bf16* cbp = (bf16*)alloc((size_t)64 * 64 * 128 * sizeof(bf16));
    float* cc = (float*)alloc(64 * sizeof(float));
    // position-major intermediates [n][row][128], rows/n: 512 / 256 / 128
    bf16* h1  = (bf16*)alloc((size_t)256 * 512 * 128 * sizeof(bf16));
    bf16* h2  = (bf16*)alloc((size_t)256 * 256 * 128 * sizeof(bf16));
    bf16* h3  = h1;  // reuse: h1 dead after conv2
    (void)alloc((size_t)1 << 20);  // slack: tile overreads past last n are in-bounds

    k_prep_wall<<<(38 * 16384 + 255) / 256, 256, 0, stream>>>(w1, w2, w3, w4, wT1, wT2, wT3, wT4);
    k_prep_c<<<64, 256, 0, stream>>>(cen, cbp, cc);

    // conv1: x fp32 1024 -> 505(512 rows) K=15, LeakyReLU; LT=64 -> 2048 blocks
    k_conv<15, 1024, 512, 64, true, true>
        <<<dim3(8, 256), 256, 0, stream>>>(x, wT1, b1, h1);
    // conv2: 505 -> 247(256 rows) K=12, LeakyReLU; LT=64 -> 1024 blocks
    k_conv<12, 512, 256, 64, true, false>
        <<<dim3(4, 256), 256, 0, stream>>>(h1, wT2, b2, h2);
    // conv3: 247 -> 121(128 rows) K=7, LeakyReLU; LT=32 -> 1024 blocks
    k_conv<7, 256, 128, 32, true, false>
        <<<dim3(4, 256), 256, 0, stream>>>(h2, wT3, b3, h3);
    // conv4 (121 -> 59, K=4) fused with distances + softmax-normalize
    k_conv4_dist<<<256, 256, 0, stream>>>(h3, wT4, b4, cbp, cc, out);
}

// Round 6
// 483.015 us; speedup vs baseline: 1.4076x; 1.2944x over previous
//
#include <hip/hip_runtime.h>

typedef __bf16 bf16;
typedef __bf16 bf16x4 __attribute__((ext_vector_type(4)));
typedef __bf16 bf16x8 __attribute__((ext_vector_type(8)));
typedef float f32x2 __attribute__((ext_vector_type(2)));
typedef float f32x4 __attribute__((ext_vector_type(4)));

#define CCH 128  // channels (all layers 128 -> 128)

// ---- prep: weights (O,I,K) fp32 -> MFMA-fragment-packed bf16 ----
// packed[((kt*4 + c)*8 + og)*512 + lane*8 + e], lane = quad*16 + m,
// o = og*16 + m, i = c*32 + quad*8 + e.
// => an A-fragment load for one wave is ONE contiguous 1KB burst.
__global__ void k_prep_wall(const float* __restrict__ w1, const float* __restrict__ w2,
                            const float* __restrict__ w3, const float* __restrict__ w4,
                            bf16* __restrict__ o1, bf16* __restrict__ o2,
                            bf16* __restrict__ o3, bf16* __restrict__ o4) {
    int idx = blockIdx.x * 256 + threadIdx.x;
    const float* src; bf16* dst; int Kw; int r = idx;
    if (r < 15 * 16384) { src = w1; dst = o1; Kw = 15; }
    else if ((r -= 15 * 16384) < 12 * 16384) { src = w2; dst = o2; Kw = 12; }
    else if ((r -= 12 * 16384) < 7 * 16384) { src = w3; dst = o3; Kw = 7; }
    else if ((r -= 7 * 16384) < 4 * 16384) { src = w4; dst = o4; Kw = 4; }
    else return;
    int e = r & 7, lane = (r >> 3) & 63, og = (r >> 9) & 7, c = (r >> 12) & 3, kt = r >> 14;
    int o = og * 16 + (lane & 15);
    int i = c * 32 + (lane >> 4) * 8 + e;
    dst[r] = (bf16)src[(o * 128 + i) * Kw + kt];
}

// ---- prep: centers fp32 -> bf16 [k][l(64, zero-pad l>=59)][o], plus ||c||^2 ----
__global__ void k_prep_c(const float* __restrict__ c, bf16* __restrict__ cbp,
                         float* __restrict__ cc) {
    int k = blockIdx.x;
    int tid = threadIdx.x;
    float s = 0.f;
    for (int idx = tid; idx < 64 * 128; idx += 256) {
        int l = idx >> 7;
        int o = idx & 127;
        float v = (l < 59) ? c[k * 7552 + o * 59 + l] : 0.f;
        bf16 b = (bf16)v;
        cbp[(size_t)k * 64 * 128 + idx] = b;
        float fv = (float)b;
        s += fv * fv;
    }
    __shared__ float red[256];
    red[tid] = s;
    __syncthreads();
    for (int st = 128; st > 0; st >>= 1) {
        if (tid < st) red[tid] += red[tid + st];
        __syncthreads();
    }
    if (tid == 0) cc[k] = red[0];
}

// ---- conv layer: implicit GEMM, bf16 MFMA, position-major activations ----
// Wave grid: 4 waves x (32 o x LT l): per j only 2 contiguous-1KB A-loads/wave,
// each feeding 4 MFMAs; B from swizzled LDS (b128, <=2-way).
// PH=2: two channel-phases of 64 (conv1, halves LDS for LT=128).
template <int KW, int IN_CAP, int OUT_ROWS, int LT, int PH, bool ACT, bool IN_CL_F32>
__global__ __launch_bounds__(256, 4) void k_conv(
    const void* __restrict__ in_, const bf16* __restrict__ wTp,
    const float* __restrict__ bias, bf16* __restrict__ out) {
    constexpr int P = (LT - 1) * 2 + KW;   // input positions needed
    constexpr int CPP = 128 / PH;          // channels per phase
    constexpr int KC = CPP / 32;           // 32-chunks per phase
    constexpr int C16N = CPP / 8;          // 16B chunks per phase
    constexpr int RS = CPP;                // LDS row stride (elems)
    constexpr int KCL = (KC == 4) ? 2 : 1;
    constexpr int PP = IN_CL_F32 ? ((P + 1) & ~1) : P;
    constexpr int NLT = LT / 16;
    constexpr int ESE = 136;               // epilogue [l][o] stride
    constexpr int SMELE = (PP * RS > LT * ESE) ? PP * RS : LT * ESE;
    constexpr int NJ = KW * KC;            // always even
    __shared__ __align__(16) bf16 smem[SMELE];

    const int n = blockIdx.y;
    const int l0 = blockIdx.x * LT;
    const int p0 = l0 * 2;
    const int tid = threadIdx.x;
    const int wid = tid >> 6;
    const int lane = tid & 63;
    const int quad = lane >> 4;
    const int l15 = lane & 15;
    const int og0 = wid * 2;               // wave owns o [wid*32, wid*32+32)

    f32x4 acc[2][NLT];
#pragma unroll
    for (int a = 0; a < 2; ++a)
#pragma unroll
        for (int b = 0; b < NLT; ++b) acc[a][b] = (f32x4){0.f, 0.f, 0.f, 0.f};

    bf16x8 afr[2][2];
    const bf16* wbase = wTp + (size_t)lane * 8;

    // initial A prefetch (kt=0, cA=0)
    afr[0][0] = *(const bf16x8*)(wbase + ((size_t)(og0 + 0) << 9));
    afr[0][1] = *(const bf16x8*)(wbase + ((size_t)(og0 + 1) << 9));

#pragma unroll 1
    for (int ph = 0; ph < PH; ++ph) {
        if (ph) __syncthreads();  // protect smem against overwrite

        if (IN_CL_F32) {
            // conv1: x fp32 [n][c][1024]; f32x2 units -> 8-bank-word scatter max
            constexpr int N2 = PP / 2;
            constexpr int UNITS = 64 * N2;
            constexpr int NIT = (UNITS + 255) / 256;
            const float* inF = (const float*)in_;
#pragma unroll
            for (int it = 0; it < NIT; ++it) {
                int u = tid + it * 256;
                if ((UNITS & 255) == 0 || u < UNITS) {
                    int iloc = u / N2;
                    int v2 = u - iloc * N2;
                    int gp0 = p0 + v2 * 2;
                    const float* row = inF + ((size_t)n * CCH + ph * 64 + iloc) * 1024;
                    float va, vb;
                    if (gp0 + 2 <= 1024) {
                        f32x2 t = *(const f32x2*)(row + gp0);
                        va = t[0]; vb = t[1];
                    } else {
                        va = (gp0 < 1024) ? row[gp0] : 0.f;
                        vb = (gp0 + 1 < 1024) ? row[gp0 + 1] : 0.f;
                    }
                    int sc = (iloc >> 3) ^ (v2 & 7);  // (p>>1)&7 == v2&7
                    int p = v2 * 2;
                    smem[p * RS + sc * 8 + (iloc & 7)] = (bf16)va;
                    smem[(p + 1) * RS + sc * 8 + (iloc & 7)] = (bf16)vb;
                }
            }
        } else {
            // bf16 position-major input: b128 load -> b128 swizzled LDS write.
            // Overreads feed only invalid output columns (slack alloc'd).
            constexpr int UNITS = P * C16N;
            constexpr int NIT = (UNITS + 255) / 256;
            const bf16* base = (const bf16*)in_ + ((size_t)n * IN_CAP + p0) * CCH + ph * CPP;
#pragma unroll
            for (int it = 0; it < NIT; ++it) {
                int u = tid + it * 256;
                if ((UNITS & 255) == 0 || u < UNITS) {
                    int p = u >> ((C16N == 16) ? 4 : 3);
                    int c = u & (C16N - 1);
                    bf16x8 t = *(const bf16x8*)(base + (size_t)p * CCH + c * 8);
                    int sc = (PH == 2) ? (c ^ ((p >> 1) & 7))
                                       : ((c & 8) | ((c & 7) ^ ((p >> 1) & 7)));
                    *(bf16x8*)(smem + p * RS + sc * 8) = t;
                }
            }
        }
        __syncthreads();

        // K-loop: j = (ktap, chunk); A double-buffered one iter ahead
#pragma unroll 2
        for (int j = 0; j < NJ; ++j) {
            int nj = j + 1, nph = ph;
            if (nj == NJ) { nj = 0; ++nph; }
            if (nph < PH) {
                int kt1 = nj >> KCL;
                int c1 = (nj & (KC - 1)) + nph * KC;
                const bf16* wp = wbase + ((size_t)((kt1 * 4 + c1) * 8 + og0) << 9);
                afr[(j + 1) & 1][0] = *(const bf16x8*)(wp);
                afr[(j + 1) & 1][1] = *(const bf16x8*)(wp + 512);
            }
            const int kt = j >> KCL;
            const int c16l = (j & (KC - 1)) * 4 + quad;
#pragma unroll
            for (int lt = 0; lt < NLT; ++lt) {
                int p = (lt * 16 + l15) * 2 + kt;
                int sc = (PH == 2) ? (c16l ^ ((p >> 1) & 7))
                                   : ((c16l & 8) | ((c16l & 7) ^ ((p >> 1) & 7)));
                bf16x8 bfr = *(const bf16x8*)(smem + p * RS + sc * 8);
                acc[0][lt] = __builtin_amdgcn_mfma_f32_16x16x32_bf16(
                    afr[j & 1][0], bfr, acc[0][lt], 0, 0, 0);
                acc[1][lt] = __builtin_amdgcn_mfma_f32_16x16x32_bf16(
                    afr[j & 1][1], bfr, acc[1][lt], 0, 0, 0);
            }
        }
    }

    // ---- epilogue: bias+act -> LDS [l][o] -> contiguous 16B stores ----
    __syncthreads();
#pragma unroll
    for (int ot = 0; ot < 2; ++ot) {
        const int o0 = wid * 32 + ot * 16 + quad * 4;
        const f32x4 bv = *(const f32x4*)(bias + o0);
#pragma unroll
        for (int lt = 0; lt < NLT; ++lt) {
            const int l = lt * 16 + l15;
            bf16x4 pk;
#pragma unroll
            for (int r = 0; r < 4; ++r) {
                float v = acc[ot][lt][r] + bv[r];
                if (ACT) v = (v > 0.f) ? v : 0.1f * v;
                pk[r] = (bf16)v;
            }
            *(bf16x4*)(smem + l * ESE + o0) = pk;
        }
    }
    __syncthreads();
    constexpr int SNIT = LT * 16 / 256;
    bf16* op = out + ((size_t)n * OUT_ROWS + l0) * CCH;
#pragma unroll
    for (int it = 0; it < SNIT; ++it) {
        int u = tid + it * 256;
        int l = u >> 4;
        int g = u & 15;
        *(bf16x8*)(op + l * CCH + g * 8) = *(const bf16x8*)(smem + l * ESE + g * 8);
    }
}

// ---- fused conv4 + distances + Student-t assignment (one block per n) ----
__global__ __launch_bounds__(256, 2) void k_conv4_dist(
    const bf16* __restrict__ in_, const bf16* __restrict__ wTp,
    const float* __restrict__ bias, const bf16* __restrict__ cbp,
    const float* __restrict__ cc, float* __restrict__ out) {
    constexpr int KW = 4, P = 130, IN_CAP = 128, NJ = 16;
    constexpr int ESE = 136;
    __shared__ __align__(16) bf16 smem[P * 128];
    __shared__ __align__(16) bf16 zmem[64 * ESE];
    __shared__ float red[256];
    __shared__ float qsh[64];

    const int n = blockIdx.x;
    const int tid = threadIdx.x;
    const int wid = tid >> 6;
    const int lane = tid & 63;
    const int quad = lane >> 4;
    const int l15 = lane & 15;
    const int og0 = wid * 2;

    f32x4 acc[2][4];
#pragma unroll
    for (int a = 0; a < 2; ++a)
#pragma unroll
        for (int b = 0; b < 4; ++b) acc[a][b] = (f32x4){0.f, 0.f, 0.f, 0.f};

    bf16x8 afr[2][2];
    const bf16* wbase = wTp + (size_t)lane * 8;
    afr[0][0] = *(const bf16x8*)(wbase + ((size_t)(og0 + 0) << 9));
    afr[0][1] = *(const bf16x8*)(wbase + ((size_t)(og0 + 1) << 9));

    {
        constexpr int UNITS = P * 16;  // 2080
        const bf16* base = in_ + (size_t)n * IN_CAP * CCH;
#pragma unroll
        for (int it = 0; it < (UNITS + 255) / 256; ++it) {
            int u = tid + it * 256;
            if (u < UNITS) {
                int p = u >> 4;
                int c = u & 15;
                bf16x8 t = *(const bf16x8*)(base + (size_t)p * CCH + c * 8);
                int sc = (c & 8) | ((c & 7) ^ ((p >> 1) & 7));
                *(bf16x8*)(smem + p * 128 + sc * 8) = t;
            }
        }
    }
    __syncthreads();

#pragma unroll 2
    for (int j = 0; j < NJ; ++j) {
        if (j + 1 < NJ) {
            int kt1 = (j + 1) >> 2;
            int c1 = (j + 1) & 3;
            const bf16* wp = wbase + ((size_t)((kt1 * 4 + c1) * 8 + og0) << 9);
            afr[(j + 1) & 1][0] = *(const bf16x8*)(wp);
            afr[(j + 1) & 1][1] = *(const bf16x8*)(wp + 512);
        }
        const int kt = j >> 2;
        const int c16l = (j & 3) * 4 + quad;
#pragma unroll
        for (int lt = 0; lt < 4; ++lt) {
            int p = (lt * 16 + l15) * 2 + kt;
            int sc = (c16l & 8) | ((c16l & 7) ^ ((p >> 1) & 7));
            bf16x8 bfr = *(const bf16x8*)(smem + p * 128 + sc * 8);
            acc[0][lt] = __builtin_amdgcn_mfma_f32_16x16x32_bf16(
                afr[j & 1][0], bfr, acc[0][lt], 0, 0, 0);
            acc[1][lt] = __builtin_amdgcn_mfma_f32_16x16x32_bf16(
                afr[j & 1][1], bfr, acc[1][lt], 0, 0, 0);
        }
    }

    // epilogue -> z bf16 [l][o], zeros l>=59 (pads match zero-padded centers)
    __syncthreads();
#pragma unroll
    for (int ot = 0; ot < 2; ++ot) {
        const int o0 = wid * 32 + ot * 16 + quad * 4;
        const f32x4 bv = *(const f32x4*)(bias + o0);
#pragma unroll
        for (int lt = 0; lt < 4; ++lt) {
            const int l = lt * 16 + l15;
            bf16x4 pk;
#pragma unroll
            for (int r = 0; r < 4; ++r) {
                float v = acc[ot][lt][r] + bv[r];
                pk[r] = (l < 59) ? (bf16)v : (bf16)0.f;
            }
            *(bf16x4*)(zmem + l * ESE + o0) = pk;
        }
    }
    __syncthreads();

    // dist: thread = (center kc = tid>>2, part = tid&3 covering 16 l-rows)
    const int kc = tid >> 2;
    const int part = tid & 3;
    const bf16* cr = cbp + ((size_t)kc * 64 + part * 16) * 128;
    const bf16* zr = zmem + part * 16 * ESE;
    float t = 0.f;
#pragma unroll 2
    for (int l = 0; l < 16; ++l) {
#pragma unroll
        for (int g = 0; g < 16; ++g) {
            bf16x8 cv = *(const bf16x8*)(cr + l * 128 + g * 8);
            bf16x8 zv = *(const bf16x8*)(zr + l * ESE + g * 8);
#pragma unroll
            for (int e = 0; e < 8; ++e) {
                float zf = (float)zv[e];
                t += zf * (zf - 2.f * (float)cv[e]);
            }
        }
    }
    red[tid] = t;
    __syncthreads();
    if (tid < 64) {
        float d2 = red[tid * 4] + red[tid * 4 + 1] + red[tid * 4 + 2] + red[tid * 4 + 3]
                   + cc[tid];
        qsh[tid] = 1.f / (1.f + d2);  // ALPHA=1, exponent (ALPHA+1)/2 == 1
    }
    __syncthreads();
    if (tid < 64) {
        float q = qsh[tid];
        float tot = q;
        for (int o = 32; o > 0; o >>= 1) tot += __shfl_down(tot, o);
        tot = __shfl(tot, 0);
        out[n * 64 + tid] = q / tot;
    }
}

// ---------------- launcher ----------------
extern "C" void kernel_launch(void* const* d_in, const int* in_sizes, int n_in,
                              void* d_out, int out_size, void* d_ws, size_t ws_size,
                              hipStream_t stream) {
    (void)in_sizes; (void)n_in; (void)out_size; (void)ws_size;
    const float* x   = (const float*)d_in[0];
    const float* w1  = (const float*)d_in[1];
    const float* b1  = (const float*)d_in[2];
    const float* w2  = (const float*)d_in[3];
    const float* b2  = (const float*)d_in[4];
    const float* w3  = (const float*)d_in[5];
    const float* b3  = (const float*)d_in[6];
    const float* w4  = (const float*)d_in[7];
    const float* b4  = (const float*)d_in[8];
    const float* cen = (const float*)d_in[9];
    float* out = (float*)d_out;

    char* ws = (char*)d_ws;
    size_t off = 0;
    auto alloc = [&](size_t bytes) -> void* {
        void* p = ws + off;
        off += (bytes + 255) & ~(size_t)255;
        return p;
    };
    bf16* wT1 = (bf16*)alloc((size_t)15 * 16384 * sizeof(bf16));
    bf16* wT2 = (bf16*)alloc((size_t)12 * 16384 * sizeof(bf16));
    bf16* wT3 = (bf16*)alloc((size_t)7 * 16384 * sizeof(bf16));
    bf16* wT4 = (bf16*)alloc((size_t)4 * 16384 * sizeof(bf16));
    bf16* cbp = (bf16*)alloc((size_t)64 * 64 * 128 * sizeof(bf16));
    float* cc = (float*)alloc(64 * sizeof(float));
    // position-major intermediates [n][row][128], rows/n: 512 / 256 / 128
    bf16* h1  = (bf16*)alloc((size_t)256 * 512 * 128 * sizeof(bf16));
    bf16* h2  = (bf16*)alloc((size_t)256 * 256 * 128 * sizeof(bf16));
    bf16* h3  = h1;  // reuse: h1 dead after conv2
    (void)alloc((size_t)1 << 20);  // slack: tile overreads stay in-bounds

    k_prep_wall<<<(38 * 16384 + 255) / 256, 256, 0, stream>>>(w1, w2, w3, w4, wT1, wT2, wT3, wT4);
    k_prep_c<<<64, 256, 0, stream>>>(cen, cbp, cc);

    // conv1: x fp32 1024 -> 505(512 rows) K=15, LeakyReLU; LT=128 two-phase
    k_conv<15, 1024, 512, 128, 2, true, true>
        <<<dim3(4, 256), 256, 0, stream>>>(x, wT1, b1, h1);
    // conv2: 505 -> 247(256 rows) K=12, LeakyReLU; LT=64 single-phase
    k_conv<12, 512, 256, 64, 1, true, false>
        <<<dim3(4, 256), 256, 0, stream>>>(h1, wT2, b2, h2);
    // conv3: 247 -> 121(128 rows) K=7, LeakyReLU; LT=64 single-phase
    k_conv<7, 256, 128, 64, 1, true, false>
        <<<dim3(2, 256), 256, 0, stream>>>(h2, wT3, b3, h3);
    // conv4 (121 -> 59, K=4) fused with distances + softmax-normalize
    k_conv4_dist<<<256, 256, 0, stream>>>(h3, wT4, b4, cbp, cc, out);
}

// Round 7
// 383.791 us; speedup vs baseline: 1.7715x; 1.2585x over previous
//
#include <hip/hip_runtime.h>

typedef __bf16 bf16;
typedef __bf16 bf16x4 __attribute__((ext_vector_type(4)));
typedef __bf16 bf16x8 __attribute__((ext_vector_type(8)));
typedef float f32x4 __attribute__((ext_vector_type(4)));

#define CCH 128  // channels (all layers 128 -> 128)

// ---- prep: weights (O,I,K) fp32 -> MFMA-fragment-packed bf16 ----
// packed[((kt*4 + c)*8 + og)*512 + lane*8 + e], lane = quad*16 + m,
// o = og*16 + m, i = c*32 + quad*8 + e.
// => an A-fragment load for one wave is ONE contiguous 1KB burst.
__global__ void k_prep_wall(const float* __restrict__ w1, const float* __restrict__ w2,
                            const float* __restrict__ w3, const float* __restrict__ w4,
                            bf16* __restrict__ o1, bf16* __restrict__ o2,
                            bf16* __restrict__ o3, bf16* __restrict__ o4) {
    int idx = blockIdx.x * 256 + threadIdx.x;
    const float* src; bf16* dst; int Kw; int r = idx;
    if (r < 15 * 16384) { src = w1; dst = o1; Kw = 15; }
    else if ((r -= 15 * 16384) < 12 * 16384) { src = w2; dst = o2; Kw = 12; }
    else if ((r -= 12 * 16384) < 7 * 16384) { src = w3; dst = o3; Kw = 7; }
    else if ((r -= 7 * 16384) < 4 * 16384) { src = w4; dst = o4; Kw = 4; }
    else return;
    int e = r & 7, lane = (r >> 3) & 63, og = (r >> 9) & 7, c = (r >> 12) & 3, kt = r >> 14;
    int o = og * 16 + (lane & 15);
    int i = c * 32 + (lane >> 4) * 8 + e;
    dst[r] = (bf16)src[(o * 128 + i) * Kw + kt];
}

// ---- prep: x [n][c][1024] f32 -> xT [n][p][128] bf16 (position-major) ----
// Memory-bound transpose+convert through an LDS tile (64 positions per block).
__global__ __launch_bounds__(256, 8) void k_prep_x(const float* __restrict__ x,
                                                   bf16* __restrict__ xT) {
    constexpr int S = 130;  // LDS row stride (pad 2)
    __shared__ __align__(16) bf16 lds[64 * S];
    const int n = blockIdx.y;
    const int p0 = blockIdx.x * 64;
    const int tid = threadIdx.x;
#pragma unroll
    for (int it = 0; it < 8; ++it) {
        int u = tid + it * 256;
        int ch = u >> 4;
        int v = u & 15;
        f32x4 t = *(const f32x4*)(x + ((size_t)n * CCH + ch) * 1024 + p0 + v * 4);
#pragma unroll
        for (int e = 0; e < 4; ++e) lds[(v * 4 + e) * S + ch] = (bf16)t[e];
    }
    __syncthreads();
    bf16* op = xT + ((size_t)n * 1024 + p0) * CCH;
#pragma unroll
    for (int it = 0; it < 4; ++it) {
        int u = tid + it * 256;
        int p = u >> 4;
        int g = u & 15;
        *(bf16x8*)(op + p * CCH + g * 8) = *(const bf16x8*)(lds + p * S + g * 8);
    }
}

// ---- prep: centers fp32 -> bf16 [k][l(64, zero-pad l>=59)][o], plus ||c||^2 ----
__global__ void k_prep_c(const float* __restrict__ c, bf16* __restrict__ cbp,
                         float* __restrict__ cc) {
    int k = blockIdx.x;
    int tid = threadIdx.x;
    float s = 0.f;
    for (int idx = tid; idx < 64 * 128; idx += 256) {
        int l = idx >> 7;
        int o = idx & 127;
        float v = (l < 59) ? c[k * 7552 + o * 59 + l] : 0.f;
        bf16 b = (bf16)v;
        cbp[(size_t)k * 64 * 128 + idx] = b;
        float fv = (float)b;
        s += fv * fv;
    }
    __shared__ float red[256];
    red[tid] = s;
    __syncthreads();
    for (int st = 128; st > 0; st >>= 1) {
        if (tid < st) red[tid] += red[tid + st];
        __syncthreads();
    }
    if (tid == 0) cc[k] = red[0];
}

// ---- conv layer: implicit GEMM, bf16 MFMA, position-major both sides ----
// Input [n][row][128] bf16 (row stride 256B). Output same layout.
// Wave grid: 4 waves x (32 o x LT l); A packed 1KB-contiguous, dbuf'd.
// PH=2: two channel-phases of 64 (halves LDS for LT=128).
// Out-of-tile overreads feed only invalid output columns (slack alloc'd).
template <int KW, int IN_CAP, int OUT_ROWS, int LT, int PH, bool ACT>
__global__ __launch_bounds__(256, 4) void k_conv(
    const bf16* __restrict__ in_, const bf16* __restrict__ wTp,
    const float* __restrict__ bias, bf16* __restrict__ out) {
    constexpr int P = (LT - 1) * 2 + KW;   // input positions needed
    constexpr int CPP = 128 / PH;          // channels per phase
    constexpr int KC = CPP / 32;           // 32-chunks per phase
    constexpr int C16N = CPP / 8;          // 16B chunks per phase
    constexpr int RS = CPP;                // LDS row stride (elems)
    constexpr int KCL = (KC == 4) ? 2 : 1;
    constexpr int NLT = LT / 16;
    constexpr int ESE = 136;               // epilogue [l][o] stride
    constexpr int SMELE = (P * RS > LT * ESE) ? P * RS : LT * ESE;
    constexpr int NJ = KW * KC;
    __shared__ __align__(16) bf16 smem[SMELE];

    const int n = blockIdx.y;
    const int l0 = blockIdx.x * LT;
    const int p0 = l0 * 2;
    const int tid = threadIdx.x;
    const int wid = tid >> 6;
    const int lane = tid & 63;
    const int quad = lane >> 4;
    const int l15 = lane & 15;
    const int og0 = wid * 2;               // wave owns o [wid*32, wid*32+32)

    f32x4 acc[2][NLT];
#pragma unroll
    for (int a = 0; a < 2; ++a)
#pragma unroll
        for (int b = 0; b < NLT; ++b) acc[a][b] = (f32x4){0.f, 0.f, 0.f, 0.f};

    bf16x8 afr[2][2];
    const bf16* wbase = wTp + (size_t)lane * 8;

    // initial A prefetch (kt=0, chunk 0)
    afr[0][0] = *(const bf16x8*)(wbase + ((size_t)(og0 + 0) << 9));
    afr[0][1] = *(const bf16x8*)(wbase + ((size_t)(og0 + 1) << 9));

#pragma unroll 1
    for (int ph = 0; ph < PH; ++ph) {
        if (ph) __syncthreads();  // protect smem against overwrite

        // stage: b128 global load -> b128 swizzled LDS write
        constexpr int UNITS = P * C16N;
        constexpr int NIT = (UNITS + 255) / 256;
        const bf16* base = in_ + ((size_t)n * IN_CAP + p0) * CCH + ph * CPP;
#pragma unroll
        for (int it = 0; it < NIT; ++it) {
            int u = tid + it * 256;
            if ((UNITS & 255) == 0 || u < UNITS) {
                int p = u >> ((C16N == 16) ? 4 : 3);
                int c = u & (C16N - 1);
                bf16x8 t = *(const bf16x8*)(base + (size_t)p * CCH + c * 8);
                int sc = (PH == 2) ? (c ^ ((p >> 1) & 7))
                                   : ((c & 8) | ((c & 7) ^ ((p >> 1) & 7)));
                *(bf16x8*)(smem + p * RS + sc * 8) = t;
            }
        }
        __syncthreads();

        // K-loop: j = (ktap, chunk); A double-buffered one iter ahead
#pragma unroll 2
        for (int j = 0; j < NJ; ++j) {
            int nj = j + 1, nph = ph;
            if (nj == NJ) { nj = 0; ++nph; }
            if (nph < PH) {
                int kt1 = nj >> KCL;
                int c1 = (nj & (KC - 1)) + nph * KC;
                const bf16* wp = wbase + ((size_t)((kt1 * 4 + c1) * 8 + og0) << 9);
                afr[(j + 1) & 1][0] = *(const bf16x8*)(wp);
                afr[(j + 1) & 1][1] = *(const bf16x8*)(wp + 512);
            }
            const int kt = j >> KCL;
            const int c16l = (j & (KC - 1)) * 4 + quad;
#pragma unroll
            for (int lt = 0; lt < NLT; ++lt) {
                int p = (lt * 16 + l15) * 2 + kt;
                int sc = (PH == 2) ? (c16l ^ ((p >> 1) & 7))
                                   : ((c16l & 8) | ((c16l & 7) ^ ((p >> 1) & 7)));
                bf16x8 bfr = *(const bf16x8*)(smem + p * RS + sc * 8);
                acc[0][lt] = __builtin_amdgcn_mfma_f32_16x16x32_bf16(
                    afr[j & 1][0], bfr, acc[0][lt], 0, 0, 0);
                acc[1][lt] = __builtin_amdgcn_mfma_f32_16x16x32_bf16(
                    afr[j & 1][1], bfr, acc[1][lt], 0, 0, 0);
            }
        }
    }

    // ---- epilogue: bias+act -> LDS [l][o] -> contiguous 16B stores ----
    __syncthreads();
#pragma unroll
    for (int ot = 0; ot < 2; ++ot) {
        const int o0 = wid * 32 + ot * 16 + quad * 4;
        const f32x4 bv = *(const f32x4*)(bias + o0);
#pragma unroll
        for (int lt = 0; lt < NLT; ++lt) {
            const int l = lt * 16 + l15;
            bf16x4 pk;
#pragma unroll
            for (int r = 0; r < 4; ++r) {
                float v = acc[ot][lt][r] + bv[r];
                if (ACT) v = (v > 0.f) ? v : 0.1f * v;
                pk[r] = (bf16)v;
            }
            *(bf16x4*)(smem + l * ESE + o0) = pk;
        }
    }
    __syncthreads();
    constexpr int SNIT = LT * 16 / 256;
    bf16* op = out + ((size_t)n * OUT_ROWS + l0) * CCH;
#pragma unroll
    for (int it = 0; it < SNIT; ++it) {
        int u = tid + it * 256;
        int l = u >> 4;
        int g = u & 15;
        *(bf16x8*)(op + l * CCH + g * 8) = *(const bf16x8*)(smem + l * ESE + g * 8);
    }
}

// ---- fused conv4 + distances + Student-t assignment (one block per n) ----
__global__ __launch_bounds__(256, 2) void k_conv4_dist(
    const bf16* __restrict__ in_, const bf16* __restrict__ wTp,
    const float* __restrict__ bias, const bf16* __restrict__ cbp,
    const float* __restrict__ cc, float* __restrict__ out) {
    constexpr int KW = 4, P = 130, IN_CAP = 128, NJ = 16;
    constexpr int ESE = 136;
    __shared__ __align__(16) bf16 smem[P * 128];
    __shared__ __align__(16) bf16 zmem[64 * ESE];
    __shared__ float red[256];
    __shared__ float qsh[64];

    const int n = blockIdx.x;
    const int tid = threadIdx.x;
    const int wid = tid >> 6;
    const int lane = tid & 63;
    const int quad = lane >> 4;
    const int l15 = lane & 15;
    const int og0 = wid * 2;

    f32x4 acc[2][4];
#pragma unroll
    for (int a = 0; a < 2; ++a)
#pragma unroll
        for (int b = 0; b < 4; ++b) acc[a][b] = (f32x4){0.f, 0.f, 0.f, 0.f};

    bf16x8 afr[2][2];
    const bf16* wbase = wTp + (size_t)lane * 8;
    afr[0][0] = *(const bf16x8*)(wbase + ((size_t)(og0 + 0) << 9));
    afr[0][1] = *(const bf16x8*)(wbase + ((size_t)(og0 + 1) << 9));

    {
        constexpr int UNITS = P * 16;  // 2080
        const bf16* base = in_ + (size_t)n * IN_CAP * CCH;
#pragma unroll
        for (int it = 0; it < (UNITS + 255) / 256; ++it) {
            int u = tid + it * 256;
            if (u < UNITS) {
                int p = u >> 4;
                int c = u & 15;
                bf16x8 t = *(const bf16x8*)(base + (size_t)p * CCH + c * 8);
                int sc = (c & 8) | ((c & 7) ^ ((p >> 1) & 7));
                *(bf16x8*)(smem + p * 128 + sc * 8) = t;
            }
        }
    }
    __syncthreads();

#pragma unroll 2
    for (int j = 0; j < NJ; ++j) {
        if (j + 1 < NJ) {
            int kt1 = (j + 1) >> 2;
            int c1 = (j + 1) & 3;
            const bf16* wp = wbase + ((size_t)((kt1 * 4 + c1) * 8 + og0) << 9);
            afr[(j + 1) & 1][0] = *(const bf16x8*)(wp);
            afr[(j + 1) & 1][1] = *(const bf16x8*)(wp + 512);
        }
        const int kt = j >> 2;
        const int c16l = (j & 3) * 4 + quad;
#pragma unroll
        for (int lt = 0; lt < 4; ++lt) {
            int p = (lt * 16 + l15) * 2 + kt;
            int sc = (c16l & 8) | ((c16l & 7) ^ ((p >> 1) & 7));
            bf16x8 bfr = *(const bf16x8*)(smem + p * 128 + sc * 8);
            acc[0][lt] = __builtin_amdgcn_mfma_f32_16x16x32_bf16(
                afr[j & 1][0], bfr, acc[0][lt], 0, 0, 0);
            acc[1][lt] = __builtin_amdgcn_mfma_f32_16x16x32_bf16(
                afr[j & 1][1], bfr, acc[1][lt], 0, 0, 0);
        }
    }

    // epilogue -> z bf16 [l][o], zeros l>=59 (pads match zero-padded centers)
    __syncthreads();
#pragma unroll
    for (int ot = 0; ot < 2; ++ot) {
        const int o0 = wid * 32 + ot * 16 + quad * 4;
        const f32x4 bv = *(const f32x4*)(bias + o0);
#pragma unroll
        for (int lt = 0; lt < 4; ++lt) {
            const int l = lt * 16 + l15;
            bf16x4 pk;
#pragma unroll
            for (int r = 0; r < 4; ++r) {
                float v = acc[ot][lt][r] + bv[r];
                pk[r] = (l < 59) ? (bf16)v : (bf16)0.f;
            }
            *(bf16x4*)(zmem + l * ESE + o0) = pk;
        }
    }
    __syncthreads();

    // dist: thread = (center kc = tid>>2, part = tid&3 covering 16 l-rows)
    const int kc = tid >> 2;
    const int part = tid & 3;
    const bf16* cr = cbp + ((size_t)kc * 64 + part * 16) * 128;
    const bf16* zr = zmem + part * 16 * ESE;
    float t = 0.f;
#pragma unroll 2
    for (int l = 0; l < 16; ++l) {
#pragma unroll
        for (int g = 0; g < 16; ++g) {
            bf16x8 cv = *(const bf16x8*)(cr + l * 128 + g * 8);
            bf16x8 zv = *(const bf16x8*)(zr + l * ESE + g * 8);
#pragma unroll
            for (int e = 0; e < 8; ++e) {
                float zf = (float)zv[e];
                t += zf * (zf - 2.f * (float)cv[e]);
            }
        }
    }
    red[tid] = t;
    __syncthreads();
    if (tid < 64) {
        float d2 = red[tid * 4] + red[tid * 4 + 1] + red[tid * 4 + 2] + red[tid * 4 + 3]
                   + cc[tid];
        qsh[tid] = 1.f / (1.f + d2);  // ALPHA=1, exponent (ALPHA+1)/2 == 1
    }
    __syncthreads();
    if (tid < 64) {
        float q = qsh[tid];
        float tot = q;
        for (int o = 32; o > 0; o >>= 1) tot += __shfl_down(tot, o);
        tot = __shfl(tot, 0);
        out[n * 64 + tid] = q / tot;
    }
}

// ---------------- launcher ----------------
extern "C" void kernel_launch(void* const* d_in, const int* in_sizes, int n_in,
                              void* d_out, int out_size, void* d_ws, size_t ws_size,
                              hipStream_t stream) {
    (void)in_sizes; (void)n_in; (void)out_size; (void)ws_size;
    const float* x   = (const float*)d_in[0];
    const float* w1  = (const float*)d_in[1];
    const float* b1  = (const float*)d_in[2];
    const float* w2  = (const float*)d_in[3];
    const float* b2  = (const float*)d_in[4];
    const float* w3  = (const float*)d_in[5];
    const float* b3  = (const float*)d_in[6];
    const float* w4  = (const float*)d_in[7];
    const float* b4  = (const float*)d_in[8];
    const float* cen = (const float*)d_in[9];
    float* out = (float*)d_out;

    char* ws = (char*)d_ws;
    size_t off = 0;
    auto alloc = [&](size_t bytes) -> void* {
        void* p = ws + off;
        off += (bytes + 255) & ~(size_t)255;
        return p;
    };
    bf16* wT1 = (bf16*)alloc((size_t)15 * 16384 * sizeof(bf16));
    bf16* wT2 = (bf16*)alloc((size_t)12 * 16384 * sizeof(bf16));
    bf16* wT3 = (bf16*)alloc((size_t)7 * 16384 * sizeof(bf16));
    bf16* wT4 = (bf16*)alloc((size_t)4 * 16384 * sizeof(bf16));
    bf16* cbp = (bf16*)alloc((size_t)64 * 64 * 128 * sizeof(bf16));
    float* cc = (float*)alloc(64 * sizeof(float));
    // position-major intermediates [n][row][128]; xT unions with h2:
    // xT (conv1 input) is dead before conv2 writes h2.
    bf16* h1  = (bf16*)alloc((size_t)256 * 512 * 128 * sizeof(bf16));
    bf16* xT  = (bf16*)alloc((size_t)256 * 1024 * 128 * sizeof(bf16));
    bf16* h2  = xT;   // union (16.8 MB inside 67 MB)
    bf16* h3  = h1;   // reuse: h1 dead after conv2
    (void)alloc((size_t)1 << 20);  // slack: tile overreads stay in-bounds

    k_prep_wall<<<(38 * 16384 + 255) / 256, 256, 0, stream>>>(w1, w2, w3, w4, wT1, wT2, wT3, wT4);
    k_prep_c<<<64, 256, 0, stream>>>(cen, cbp, cc);
    k_prep_x<<<dim3(16, 256), 256, 0, stream>>>(x, xT);

    // conv1: xT 1024 -> 505(512 rows) K=15, LeakyReLU; LT=128 two-phase
    k_conv<15, 1024, 512, 128, 2, true>
        <<<dim3(4, 256), 256, 0, stream>>>(xT, wT1, b1, h1);
    // conv2: 505 -> 247(256 rows) K=12, LeakyReLU; LT=64 single-phase
    k_conv<12, 512, 256, 64, 1, true>
        <<<dim3(4, 256), 256, 0, stream>>>(h1, wT2, b2, h2);
    // conv3: 247 -> 121(128 rows) K=7, LeakyReLU; LT=64 single-phase
    k_conv<7, 256, 128, 64, 1, true>
        <<<dim3(2, 256), 256, 0, stream>>>(h2, wT3, b3, h3);
    // conv4 (121 -> 59, K=4) fused with distances + softmax-normalize
    k_conv4_dist<<<256, 256, 0, stream>>>(h3, wT4, b4, cbp, cc, out);
}

// Round 8
// 372.039 us; speedup vs baseline: 1.8274x; 1.0316x over previous
//
#include <hip/hip_runtime.h>

typedef __bf16 bf16;
typedef __bf16 bf16x4 __attribute__((ext_vector_type(4)));
typedef __bf16 bf16x8 __attribute__((ext_vector_type(8)));
typedef float f32x4 __attribute__((ext_vector_type(4)));

#define CCH 128  // channels (all layers 128 -> 128)

// ---- prep: weights (O,I,K) fp32 -> MFMA-fragment-packed bf16 ----
// packed[((kt*4 + c)*8 + og)*512 + lane*8 + e], lane = quad*16 + m,
// o = og*16 + m, i = c*32 + quad*8 + e.
// => an A-fragment load for one wave is ONE contiguous 1KB burst.
__global__ void k_prep_wall(const float* __restrict__ w1, const float* __restrict__ w2,
                            const float* __restrict__ w3, const float* __restrict__ w4,
                            bf16* __restrict__ o1, bf16* __restrict__ o2,
                            bf16* __restrict__ o3, bf16* __restrict__ o4) {
    int idx = blockIdx.x * 256 + threadIdx.x;
    const float* src; bf16* dst; int Kw; int r = idx;
    if (r < 15 * 16384) { src = w1; dst = o1; Kw = 15; }
    else if ((r -= 15 * 16384) < 12 * 16384) { src = w2; dst = o2; Kw = 12; }
    else if ((r -= 12 * 16384) < 7 * 16384) { src = w3; dst = o3; Kw = 7; }
    else if ((r -= 7 * 16384) < 4 * 16384) { src = w4; dst = o4; Kw = 4; }
    else return;
    int e = r & 7, lane = (r >> 3) & 63, og = (r >> 9) & 7, c = (r >> 12) & 3, kt = r >> 14;
    int o = og * 16 + (lane & 15);
    int i = c * 32 + (lane >> 4) * 8 + e;
    dst[r] = (bf16)src[(o * 128 + i) * Kw + kt];
}

// ---- prep: x [n][c][1024] f32 -> xT [n][p][128] bf16 (position-major) ----
__global__ __launch_bounds__(256, 8) void k_prep_x(const float* __restrict__ x,
                                                   bf16* __restrict__ xT) {
    constexpr int S = 130;  // LDS row stride (pad 2)
    __shared__ __align__(16) bf16 lds[64 * S];
    const int n = blockIdx.y;
    const int p0 = blockIdx.x * 64;
    const int tid = threadIdx.x;
#pragma unroll
    for (int it = 0; it < 8; ++it) {
        int u = tid + it * 256;
        int ch = u >> 4;
        int v = u & 15;
        f32x4 t = *(const f32x4*)(x + ((size_t)n * CCH + ch) * 1024 + p0 + v * 4);
#pragma unroll
        for (int e = 0; e < 4; ++e) lds[(v * 4 + e) * S + ch] = (bf16)t[e];
    }
    __syncthreads();
    bf16* op = xT + ((size_t)n * 1024 + p0) * CCH;
#pragma unroll
    for (int it = 0; it < 4; ++it) {
        int u = tid + it * 256;
        int p = u >> 4;
        int g = u & 15;
        *(bf16x8*)(op + p * CCH + g * 8) = *(const bf16x8*)(lds + p * S + g * 8);
    }
}

// ---- prep: centers fp32 -> bf16 [k][l(64, zero-pad l>=59)][o], plus ||c||^2 ----
__global__ void k_prep_c(const float* __restrict__ c, bf16* __restrict__ cbp,
                         float* __restrict__ cc) {
    int k = blockIdx.x;
    int tid = threadIdx.x;
    float s = 0.f;
    for (int idx = tid; idx < 64 * 128; idx += 256) {
        int l = idx >> 7;
        int o = idx & 127;
        float v = (l < 59) ? c[k * 7552 + o * 59 + l] : 0.f;
        bf16 b = (bf16)v;
        cbp[(size_t)k * 64 * 128 + idx] = b;
        float fv = (float)b;
        s += fv * fv;
    }
    __shared__ float red[256];
    red[tid] = s;
    __syncthreads();
    for (int st = 128; st > 0; st >>= 1) {
        if (tid < st) red[tid] += red[tid + st];
        __syncthreads();
    }
    if (tid == 0) cc[k] = red[0];
}

// ---- conv layer: implicit GEMM, bf16 MFMA, position-major both sides ----
template <int KW, int IN_CAP, int OUT_ROWS, int LT, int PH, bool ACT>
__global__ __launch_bounds__(256, 4) void k_conv(
    const bf16* __restrict__ in_, const bf16* __restrict__ wTp,
    const float* __restrict__ bias, bf16* __restrict__ out) {
    constexpr int P = (LT - 1) * 2 + KW;   // input positions needed
    constexpr int CPP = 128 / PH;          // channels per phase
    constexpr int KC = CPP / 32;           // 32-chunks per phase
    constexpr int C16N = CPP / 8;          // 16B chunks per phase
    constexpr int RS = CPP;                // LDS row stride (elems)
    constexpr int KCL = (KC == 4) ? 2 : 1;
    constexpr int NLT = LT / 16;
    constexpr int ESE = 136;               // epilogue [l][o] stride
    constexpr int SMELE = (P * RS > LT * ESE) ? P * RS : LT * ESE;
    constexpr int NJ = KW * KC;
    __shared__ __align__(16) bf16 smem[SMELE];

    const int n = blockIdx.y;
    const int l0 = blockIdx.x * LT;
    const int p0 = l0 * 2;
    const int tid = threadIdx.x;
    const int wid = tid >> 6;
    const int lane = tid & 63;
    const int quad = lane >> 4;
    const int l15 = lane & 15;
    const int og0 = wid * 2;               // wave owns o [wid*32, wid*32+32)

    f32x4 acc[2][NLT];
#pragma unroll
    for (int a = 0; a < 2; ++a)
#pragma unroll
        for (int b = 0; b < NLT; ++b) acc[a][b] = (f32x4){0.f, 0.f, 0.f, 0.f};

    bf16x8 afr[2][2];
    const bf16* wbase = wTp + (size_t)lane * 8;

    afr[0][0] = *(const bf16x8*)(wbase + ((size_t)(og0 + 0) << 9));
    afr[0][1] = *(const bf16x8*)(wbase + ((size_t)(og0 + 1) << 9));

#pragma unroll 1
    for (int ph = 0; ph < PH; ++ph) {
        if (ph) __syncthreads();  // protect smem against overwrite

        constexpr int UNITS = P * C16N;
        constexpr int NIT = (UNITS + 255) / 256;
        const bf16* base = in_ + ((size_t)n * IN_CAP + p0) * CCH + ph * CPP;
#pragma unroll
        for (int it = 0; it < NIT; ++it) {
            int u = tid + it * 256;
            if ((UNITS & 255) == 0 || u < UNITS) {
                int p = u >> ((C16N == 16) ? 4 : 3);
                int c = u & (C16N - 1);
                bf16x8 t = *(const bf16x8*)(base + (size_t)p * CCH + c * 8);
                int sc = (PH == 2) ? (c ^ ((p >> 1) & 7))
                                   : ((c & 8) | ((c & 7) ^ ((p >> 1) & 7)));
                *(bf16x8*)(smem + p * RS + sc * 8) = t;
            }
        }
        __syncthreads();

#pragma unroll 2
        for (int j = 0; j < NJ; ++j) {
            int nj = j + 1, nph = ph;
            if (nj == NJ) { nj = 0; ++nph; }
            if (nph < PH) {
                int kt1 = nj >> KCL;
                int c1 = (nj & (KC - 1)) + nph * KC;
                const bf16* wp = wbase + ((size_t)((kt1 * 4 + c1) * 8 + og0) << 9);
                afr[(j + 1) & 1][0] = *(const bf16x8*)(wp);
                afr[(j + 1) & 1][1] = *(const bf16x8*)(wp + 512);
            }
            const int kt = j >> KCL;
            const int c16l = (j & (KC - 1)) * 4 + quad;
#pragma unroll
            for (int lt = 0; lt < NLT; ++lt) {
                int p = (lt * 16 + l15) * 2 + kt;
                int sc = (PH == 2) ? (c16l ^ ((p >> 1) & 7))
                                   : ((c16l & 8) | ((c16l & 7) ^ ((p >> 1) & 7)));
                bf16x8 bfr = *(const bf16x8*)(smem + p * RS + sc * 8);
                acc[0][lt] = __builtin_amdgcn_mfma_f32_16x16x32_bf16(
                    afr[j & 1][0], bfr, acc[0][lt], 0, 0, 0);
                acc[1][lt] = __builtin_amdgcn_mfma_f32_16x16x32_bf16(
                    afr[j & 1][1], bfr, acc[1][lt], 0, 0, 0);
            }
        }
    }

    // ---- epilogue: bias+act -> LDS [l][o] -> contiguous 16B stores ----
    __syncthreads();
#pragma unroll
    for (int ot = 0; ot < 2; ++ot) {
        const int o0 = wid * 32 + ot * 16 + quad * 4;
        const f32x4 bv = *(const f32x4*)(bias + o0);
#pragma unroll
        for (int lt = 0; lt < NLT; ++lt) {
            const int l = lt * 16 + l15;
            bf16x4 pk;
#pragma unroll
            for (int r = 0; r < 4; ++r) {
                float v = acc[ot][lt][r] + bv[r];
                if (ACT) v = (v > 0.f) ? v : 0.1f * v;
                pk[r] = (bf16)v;
            }
            *(bf16x4*)(smem + l * ESE + o0) = pk;
        }
    }
    __syncthreads();
    constexpr int SNIT = LT * 16 / 256;
    bf16* op = out + ((size_t)n * OUT_ROWS + l0) * CCH;
#pragma unroll
    for (int it = 0; it < SNIT; ++it) {
        int u = tid + it * 256;
        int l = u >> 4;
        int g = u & 15;
        *(bf16x8*)(op + l * CCH + g * 8) = *(const bf16x8*)(smem + l * ESE + g * 8);
    }
}

// ---- fused conv4 + distances + Student-t assignment (one block per n) ----
// 512 threads (2 waves/SIMD). conv4: 8 waves x (16o x 64l). Dist: per pass,
// each wave owns one center; cbp reads are lane-contiguous 1KB bursts;
// shuffle allreduce per center.
__global__ __launch_bounds__(512, 1) void k_conv4_dist(
    const bf16* __restrict__ in_, const bf16* __restrict__ wTp,
    const float* __restrict__ bias, const bf16* __restrict__ cbp,
    const float* __restrict__ cc, float* __restrict__ out) {
    constexpr int P = 130, NJ = 16;
    constexpr int ESE = 136;
    __shared__ __align__(16) bf16 smem[P * 128];
    __shared__ __align__(16) bf16 zmem[64 * ESE];
    __shared__ float d2s[64];

    const int n = blockIdx.x;
    const int tid = threadIdx.x;
    const int wid = tid >> 6;     // 0..7
    const int lane = tid & 63;
    const int quad = lane >> 4;
    const int l15 = lane & 15;

    f32x4 acc[4];
#pragma unroll
    for (int b = 0; b < 4; ++b) acc[b] = (f32x4){0.f, 0.f, 0.f, 0.f};

    bf16x8 afr[2];
    const bf16* wbase = wTp + (size_t)lane * 8;
    afr[0] = *(const bf16x8*)(wbase + ((size_t)wid << 9));  // kt=0,c=0,og=wid

    {
        constexpr int UNITS = P * 16;  // 2080
        const bf16* base = in_ + (size_t)n * 128 * CCH;
#pragma unroll
        for (int it = 0; it < 5; ++it) {
            int u = tid + it * 512;
            if (u < UNITS) {
                int p = u >> 4;
                int c = u & 15;
                bf16x8 t = *(const bf16x8*)(base + (size_t)p * CCH + c * 8);
                int sc = (c & 8) | ((c & 7) ^ ((p >> 1) & 7));
                *(bf16x8*)(smem + p * 128 + sc * 8) = t;
            }
        }
    }
    __syncthreads();

#pragma unroll 2
    for (int j = 0; j < NJ; ++j) {
        if (j + 1 < NJ) {
            int kt1 = (j + 1) >> 2;
            int c1 = (j + 1) & 3;
            afr[(j + 1) & 1] =
                *(const bf16x8*)(wbase + ((size_t)((kt1 * 4 + c1) * 8 + wid) << 9));
        }
        const int kt = j >> 2;
        const int c16l = (j & 3) * 4 + quad;
#pragma unroll
        for (int lt = 0; lt < 4; ++lt) {
            int p = (lt * 16 + l15) * 2 + kt;
            int sc = (c16l & 8) | ((c16l & 7) ^ ((p >> 1) & 7));
            bf16x8 bfr = *(const bf16x8*)(smem + p * 128 + sc * 8);
            acc[lt] = __builtin_amdgcn_mfma_f32_16x16x32_bf16(afr[j & 1], bfr, acc[lt], 0, 0, 0);
        }
    }

    // epilogue -> z bf16 [l][o], zeros l>=59 (pads match zero-padded centers)
    {
        const int o0 = wid * 16 + quad * 4;
        const f32x4 bv = *(const f32x4*)(bias + o0);
#pragma unroll
        for (int lt = 0; lt < 4; ++lt) {
            const int l = lt * 16 + l15;
            bf16x4 pk;
#pragma unroll
            for (int r = 0; r < 4; ++r) {
                float v = acc[lt][r] + bv[r];
                pk[r] = (l < 59) ? (bf16)v : (bf16)0.f;
            }
            *(bf16x4*)(zmem + l * ESE + o0) = pk;
        }
    }
    __syncthreads();

    // dist: 8 passes, wave wid owns center kc = cp*8 + wid.
    // cbp row reads: lane-contiguous 1KB per instruction (fully coalesced).
#pragma unroll 1
    for (int cp = 0; cp < 8; ++cp) {
        const int kc = cp * 8 + wid;
        const bf16* cr = cbp + (size_t)kc * 8192;
        float t = 0.f;
#pragma unroll
        for (int it = 0; it < 16; ++it) {
            int ci = it * 64 + lane;
            int l = ci >> 4;
            int g = ci & 15;
            bf16x8 cv = *(const bf16x8*)(cr + ci * 8);
            bf16x8 zv = *(const bf16x8*)(zmem + l * ESE + g * 8);
#pragma unroll
            for (int e = 0; e < 8; ++e) {
                float zf = (float)zv[e];
                t += zf * (zf - 2.f * (float)cv[e]);
            }
        }
#pragma unroll
        for (int o = 32; o > 0; o >>= 1) t += __shfl_xor(t, o);
        if (lane == 0) d2s[kc] = t + cc[kc];
    }
    __syncthreads();
    if (tid < 64) {
        float q = 1.f / (1.f + d2s[tid]);  // ALPHA=1, exponent (ALPHA+1)/2 == 1
        float tot = q;
#pragma unroll
        for (int o = 32; o > 0; o >>= 1) tot += __shfl_xor(tot, o);
        out[n * 64 + tid] = q / tot;
    }
}

// ---------------- launcher ----------------
extern "C" void kernel_launch(void* const* d_in, const int* in_sizes, int n_in,
                              void* d_out, int out_size, void* d_ws, size_t ws_size,
                              hipStream_t stream) {
    (void)in_sizes; (void)n_in; (void)out_size; (void)ws_size;
    const float* x   = (const float*)d_in[0];
    const float* w1  = (const float*)d_in[1];
    const float* b1  = (const float*)d_in[2];
    const float* w2  = (const float*)d_in[3];
    const float* b2  = (const float*)d_in[4];
    const float* w3  = (const float*)d_in[5];
    const float* b3  = (const float*)d_in[6];
    const float* w4  = (const float*)d_in[7];
    const float* b4  = (const float*)d_in[8];
    const float* cen = (const float*)d_in[9];
    float* out = (float*)d_out;

    char* ws = (char*)d_ws;
    size_t off = 0;
    auto alloc = [&](size_t bytes) -> void* {
        void* p = ws + off;
        off += (bytes + 255) & ~(size_t)255;
        return p;
    };
    bf16* wT1 = (bf16*)alloc((size_t)15 * 16384 * sizeof(bf16));
    bf16* wT2 = (bf16*)alloc((size_t)12 * 16384 * sizeof(bf16));
    bf16* wT3 = (bf16*)alloc((size_t)7 * 16384 * sizeof(bf16));
    bf16* wT4 = (bf16*)alloc((size_t)4 * 16384 * sizeof(bf16));
    bf16* cbp = (bf16*)alloc((size_t)64 * 64 * 128 * sizeof(bf16));
    float* cc = (float*)alloc(64 * sizeof(float));
    // position-major intermediates [n][row][128]; xT unions with h2:
    // xT (conv1 input) is dead before conv2 writes h2.
    bf16* h1  = (bf16*)alloc((size_t)256 * 512 * 128 * sizeof(bf16));
    bf16* xT  = (bf16*)alloc((size_t)256 * 1024 * 128 * sizeof(bf16));
    bf16* h2  = xT;   // union (16.8 MB inside 67 MB)
    bf16* h3  = h1;   // reuse: h1 dead after conv2
    (void)alloc((size_t)1 << 20);  // slack: tile overreads stay in-bounds

    k_prep_wall<<<(38 * 16384 + 255) / 256, 256, 0, stream>>>(w1, w2, w3, w4, wT1, wT2, wT3, wT4);
    k_prep_c<<<64, 256, 0, stream>>>(cen, cbp, cc);
    k_prep_x<<<dim3(16, 256), 256, 0, stream>>>(x, xT);

    // conv1: xT 1024 -> 505(512 rows) K=15, LeakyReLU; LT=128 two-phase
    k_conv<15, 1024, 512, 128, 2, true>
        <<<dim3(4, 256), 256, 0, stream>>>(xT, wT1, b1, h1);
    // conv2: 505 -> 247(256 rows) K=12, LeakyReLU; LT=64 -> 1024 blocks
    k_conv<12, 512, 256, 64, 1, true>
        <<<dim3(4, 256), 256, 0, stream>>>(h1, wT2, b2, h2);
    // conv3: 247 -> 121(128 rows) K=7, LeakyReLU; LT=32 -> 1024 blocks
    k_conv<7, 256, 128, 32, 1, true>
        <<<dim3(4, 256), 256, 0, stream>>>(h2, wT3, b3, h3);
    // conv4 (121 -> 59, K=4) fused with distances + softmax-normalize; 512 thr
    k_conv4_dist<<<256, 512, 0, stream>>>(h3, wT4, b4, cbp, cc, out);
}